// Round 12
// baseline (94.726 us; speedup 1.0000x reference)
//
#include <hip/hip_runtime.h>

#define NQ 4
#define DIM 16
#define E 3   // batch elements per thread

// Round 12: double-angle basis.
//   hh_a hh_c (half-angle products) are linear in u = (1,cos x0,sin x0)x(1,cos x1,sin x1)
//   => o_q = u^T H_q v, H = (1/16) T G T^T, 9x9 fv4 table (81 LDS reads vs 100),
//   full-angle sincos in main (no 0.5 factor). E=3 balances LDS pipe (~8.6us)
//   vs VALU (~11.5us) at ~90 live VGPRs.

typedef __attribute__((ext_vector_type(4))) float fv4;

constexpr int PA[10] = {0,0,0,0,1,1,1,2,2,3};
constexpr int PC[10] = {0,1,2,3,1,2,3,2,3,3};

// TC[ac][i]: coefficient (x1/4) of basis u_i (i = 3*i0+i1, f = {1, cos, sin})
// in hh_{PA[ac]} * hh_{PC[ac]}. Same matrix applies to the ll side (x2,x3).
__device__ constexpr float TC[10][9] = {
    {1, 1, 0,  1, 1, 0,  0, 0, 0},   // (0,0): (1+c0)(1+c1)
    {0, 0, 1,  0, 0, 1,  0, 0, 0},   // (0,1): (1+c0) s1
    {0, 0, 0,  0, 0, 0,  1, 1, 0},   // (0,2): s0 (1+c1)
    {0, 0, 0,  0, 0, 0,  0, 0, 1},   // (0,3): s0 s1
    {1,-1, 0,  1,-1, 0,  0, 0, 0},   // (1,1): (1+c0)(1-c1)
    {0, 0, 0,  0, 0, 0,  0, 0, 1},   // (1,2): s0 s1
    {0, 0, 0,  0, 0, 0,  1,-1, 0},   // (1,3): s0 (1-c1)
    {1, 1, 0, -1,-1, 0,  0, 0, 0},   // (2,2): (1-c0)(1+c1)
    {0, 0, 1,  0, 0,-1,  0, 0, 0},   // (2,3): (1-c0) s1
    {1,-1, 0, -1, 1, 0,  0, 0, 0},   // (3,3): (1-c0)(1-c1)
};

__global__ void __launch_bounds__(128)
qlayer_prep(const float* __restrict__ weights, fv4* __restrict__ hw)
{
    __shared__ __align__(16) float2 WT[DIM][DIM];   // WT[j][i] = W[i][j]
    __shared__ __align__(16) fv4 G4[100];

    // ---- phase 1: threads 0..15 build W columns (verified R1-R11) ----
    if (threadIdx.x < DIM) {
        const int k = threadIdx.x;
        float sre[DIM], sim[DIM];
#pragma unroll
        for (int i = 0; i < DIM; ++i) { sre[i] = (i == k) ? 1.f : 0.f; sim[i] = 0.f; }
#pragma unroll
        for (int l = 0; l < 3; ++l) {
#pragma unroll
            for (int p = 0; p < NQ; ++p) {
                const float h = 0.5f * weights[l * NQ + p];
                const float s = __sinf(h), c = __cosf(h);
                const int mask = 1 << (NQ - 1 - p);
#pragma unroll
                for (int i = 0; i < DIM; ++i) {
                    if (i & mask) continue;
                    const int jj = i | mask;
                    const float ar = sre[i], ai = sim[i];
                    const float br = sre[jj], bi = sim[jj];
                    sre[i]  = c * ar + s * bi;
                    sim[i]  = c * ai - s * br;
                    sre[jj] = c * br + s * ai;
                    sim[jj] = c * bi - s * ar;
                }
            }
#pragma unroll
            for (int p = 0; p < NQ; ++p) {
                const int t = (p + 1) % NQ;
                float tr[DIM], ti[DIM];
#pragma unroll
                for (int i = 0; i < DIM; ++i) {
                    const int src = i ^ ((((i >> (NQ - 1 - p)) & 1)) << (NQ - 1 - t));
                    tr[i] = sre[src]; ti[i] = sim[src];
                }
#pragma unroll
                for (int i = 0; i < DIM; ++i) { sre[i] = tr[i]; sim[i] = ti[i]; }
            }
        }
#pragma unroll
        for (int i = 0; i < DIM; ++i) WT[k][i] = make_float2(sre[i], sim[i]);
    }
    __syncthreads();

    // ---- phase 2: threads 0..99 build the folded G table (verified R2-R11) ----
    if (threadIdx.x < 100) {
        const int ac = threadIdx.x / 10, bd = threadIdx.x % 10;
        const int a = PA[ac], c = PC[ac], b = PA[bd], d = PC[bd];

        auto evalS = [&](int j, int k, float* sv) {
            float ar[4] = {0,0,0,0}, ai[4] = {0,0,0,0};
#pragma unroll
            for (int i = 0; i < DIM; ++i) {
                const float2 wj = WT[j][i], wk = WT[k][i];
                const float pr = wj.x * wk.x + wj.y * wk.y;
                const float pi = wj.x * wk.y - wj.y * wk.x;
#pragma unroll
                for (int q = 0; q < 4; ++q) {
                    const float s = ((i >> (3 - q)) & 1) ? -1.f : 1.f;
                    ar[q] += s * pr; ai[q] += s * pi;
                }
            }
            const int m = (__builtin_popcount(j) - __builtin_popcount(k)) & 3;
#pragma unroll
            for (int q = 0; q < 4; ++q)
                sv[q] = (m == 0) ? ar[q] : (m == 1) ? -ai[q] : (m == 2) ? -ar[q] : ai[q];
        };

        float s1[4], s2[4];
        evalS(4 * a + b, 4 * c + d, s1);
        evalS(4 * a + d, 4 * c + b, s2);
        const float u = ((a < c) ? 2.f : 1.f) * ((b < d) ? 1.f : 0.5f);
        fv4 gv; gv.x = u*(s1[0]+s2[0]); gv.y = u*(s1[1]+s2[1]);
        gv.z = u*(s1[2]+s2[2]); gv.w = u*(s1[3]+s2[3]);
        G4[ac * 10 + bd] = gv;
    }
    __syncthreads();

    // ---- phase 3: threads 0..80 fold basis change: H = (1/16) T G T^T ----
    if (threadIdx.x < 81) {
        const int i = threadIdx.x / 9, j = threadIdx.x % 9;
        fv4 acc = (fv4)(0.f);
#pragma unroll
        for (int ac = 0; ac < 10; ++ac) {
            const float ti = TC[ac][i];
            fv4 tj = (fv4)(0.f);
#pragma unroll
            for (int bd = 0; bd < 10; ++bd)
                tj += G4[ac * 10 + bd] * TC[bd][j];
            acc += tj * ti;
        }
        hw[i * 9 + j] = acc * 0.0625f;
    }
}

__global__ void __launch_bounds__(256)
qlayer_main(const float4* __restrict__ x,
            const fv4* __restrict__ hw,
            fv4* __restrict__ out, int B)
{
    __shared__ __align__(16) fv4 H4[81];
    if (threadIdx.x < 81) H4[threadIdx.x] = hw[threadIdx.x];
    __syncthreads();

    const int base = blockIdx.x * (256 * E) + threadIdx.x;

    float u[E][8], v[E][8];
    fv4 o[E];
    bool ok[E];

#pragma unroll
    for (int e = 0; e < E; ++e) {
        const int gi = base + e * 256;
        ok[e] = gi < B;
        const float4 xv = ok[e] ? x[gi] : make_float4(0.f, 0.f, 0.f, 0.f);
        const float cx0 = __cosf(xv.x), sx0 = __sinf(xv.x);   // FULL angles
        const float cx1 = __cosf(xv.y), sx1 = __sinf(xv.y);
        const float cx2 = __cosf(xv.z), sx2 = __sinf(xv.z);
        const float cx3 = __cosf(xv.w), sx3 = __sinf(xv.w);
        u[e][0] = cx1;       u[e][1] = sx1;       u[e][2] = cx0;
        u[e][3] = cx0 * cx1; u[e][4] = cx0 * sx1;
        u[e][5] = sx0;       u[e][6] = sx0 * cx1; u[e][7] = sx0 * sx1;
        v[e][0] = cx3;       v[e][1] = sx3;       v[e][2] = cx2;
        v[e][3] = cx2 * cx3; v[e][4] = cx2 * sx3;
        v[e][5] = sx2;       v[e][6] = sx2 * cx3; v[e][7] = sx2 * sx3;
    }

#pragma unroll
    for (int i = 0; i < 9; ++i) {
        fv4 t[E];
        {
            const fv4 g0 = H4[i * 9];                  // j = 0 term (v_0 = 1)
#pragma unroll
            for (int e = 0; e < E; ++e) t[e] = g0;
        }
#pragma unroll
        for (int j = 1; j < 9; ++j) {
            const fv4 g = H4[i * 9 + j];               // broadcast ds_read_b128
#pragma unroll
            for (int e = 0; e < E; ++e) t[e] += g * v[e][j - 1];
        }
        if (i == 0) {
#pragma unroll
            for (int e = 0; e < E; ++e) o[e] = t[e];   // u_0 = 1
        } else {
#pragma unroll
            for (int e = 0; e < E; ++e) o[e] += t[e] * u[e][i - 1];
        }
    }

#pragma unroll
    for (int e = 0; e < E; ++e) {
        const int gi = base + e * 256;
        if (ok[e]) out[gi] = o[e];
    }
}

extern "C" void kernel_launch(void* const* d_in, const int* in_sizes, int n_in,
                              void* d_out, int out_size, void* d_ws, size_t ws_size,
                              hipStream_t stream)
{
    const float4* x = (const float4*)d_in[0];
    const float* w  = (const float*)d_in[1];
    fv4* out        = (fv4*)d_out;
    fv4* hw         = (fv4*)d_ws;     // 81 * 16 B = 1296 B
    const int B = in_sizes[0] / NQ;

    qlayer_prep<<<1, 128, 0, stream>>>(w, hw);

    const int block = 256;
    const int perBlock = block * E;
    const int grid = (B + perBlock - 1) / perBlock;
    qlayer_main<<<grid, block, 0, stream>>>(x, hw, out, B);
}

// Round 13
// 80.478 us; speedup vs baseline: 1.1770x; 1.1770x over previous
//
#include <hip/hip_runtime.h>

#define NQ 4
#define DIM 16

// Round 13: E=1 (the only structure that ever beat the pack: R11) + 9x9
// double-angle table (verified R12) + NO LDS in main: H is wave-uniform,
// compile-time indexed, read-only -> LLVM uniform-load lowering emits
// s_load_dwordx4 (scalar pipe), freeing the 32us/dispatch LDS-issue bound
// that capped R11. o_q = u^T H_q v, u/v = full-angle {1,cos,sin} tensor bases.

typedef __attribute__((ext_vector_type(4))) float fv4;

constexpr int PA[10] = {0,0,0,0,1,1,1,2,2,3};
constexpr int PC[10] = {0,1,2,3,1,2,3,2,3,3};

// TC[ac][i]: coefficient (x1/4) of basis u_i (i = 3*i0+i1, f = {1, cos, sin})
// in hh_{PA[ac]} * hh_{PC[ac]}. Same matrix applies to the ll side (x2,x3).
__device__ constexpr float TC[10][9] = {
    {1, 1, 0,  1, 1, 0,  0, 0, 0},   // (0,0): (1+c0)(1+c1)
    {0, 0, 1,  0, 0, 1,  0, 0, 0},   // (0,1): (1+c0) s1
    {0, 0, 0,  0, 0, 0,  1, 1, 0},   // (0,2): s0 (1+c1)
    {0, 0, 0,  0, 0, 0,  0, 0, 1},   // (0,3): s0 s1
    {1,-1, 0,  1,-1, 0,  0, 0, 0},   // (1,1): (1+c0)(1-c1)
    {0, 0, 0,  0, 0, 0,  0, 0, 1},   // (1,2): s0 s1
    {0, 0, 0,  0, 0, 0,  1,-1, 0},   // (1,3): s0 (1-c1)
    {1, 1, 0, -1,-1, 0,  0, 0, 0},   // (2,2): (1-c0)(1+c1)
    {0, 0, 1,  0, 0,-1,  0, 0, 0},   // (2,3): (1-c0) s1
    {1,-1, 0, -1, 1, 0,  0, 0, 0},   // (3,3): (1-c0)(1-c1)
};

__global__ void __launch_bounds__(128)
qlayer_prep(const float* __restrict__ weights, fv4* __restrict__ hw)
{
    __shared__ __align__(16) float2 WT[DIM][DIM];   // WT[j][i] = W[i][j]
    __shared__ __align__(16) fv4 G4[100];

    // ---- phase 1: threads 0..15 build W columns (verified R1-R12) ----
    if (threadIdx.x < DIM) {
        const int k = threadIdx.x;
        float sre[DIM], sim[DIM];
#pragma unroll
        for (int i = 0; i < DIM; ++i) { sre[i] = (i == k) ? 1.f : 0.f; sim[i] = 0.f; }
#pragma unroll
        for (int l = 0; l < 3; ++l) {
#pragma unroll
            for (int p = 0; p < NQ; ++p) {
                const float h = 0.5f * weights[l * NQ + p];
                const float s = __sinf(h), c = __cosf(h);
                const int mask = 1 << (NQ - 1 - p);
#pragma unroll
                for (int i = 0; i < DIM; ++i) {
                    if (i & mask) continue;
                    const int jj = i | mask;
                    const float ar = sre[i], ai = sim[i];
                    const float br = sre[jj], bi = sim[jj];
                    sre[i]  = c * ar + s * bi;
                    sim[i]  = c * ai - s * br;
                    sre[jj] = c * br + s * ai;
                    sim[jj] = c * bi - s * ar;
                }
            }
#pragma unroll
            for (int p = 0; p < NQ; ++p) {
                const int t = (p + 1) % NQ;
                float tr[DIM], ti[DIM];
#pragma unroll
                for (int i = 0; i < DIM; ++i) {
                    const int src = i ^ ((((i >> (NQ - 1 - p)) & 1)) << (NQ - 1 - t));
                    tr[i] = sre[src]; ti[i] = sim[src];
                }
#pragma unroll
                for (int i = 0; i < DIM; ++i) { sre[i] = tr[i]; sim[i] = ti[i]; }
            }
        }
#pragma unroll
        for (int i = 0; i < DIM; ++i) WT[k][i] = make_float2(sre[i], sim[i]);
    }
    __syncthreads();

    // ---- phase 2: threads 0..99 build folded G table (verified R2-R12) ----
    if (threadIdx.x < 100) {
        const int ac = threadIdx.x / 10, bd = threadIdx.x % 10;
        const int a = PA[ac], c = PC[ac], b = PA[bd], d = PC[bd];

        auto evalS = [&](int j, int k, float* sv) {
            float ar[4] = {0,0,0,0}, ai[4] = {0,0,0,0};
#pragma unroll
            for (int i = 0; i < DIM; ++i) {
                const float2 wj = WT[j][i], wk = WT[k][i];
                const float pr = wj.x * wk.x + wj.y * wk.y;
                const float pi = wj.x * wk.y - wj.y * wk.x;
#pragma unroll
                for (int q = 0; q < 4; ++q) {
                    const float s = ((i >> (3 - q)) & 1) ? -1.f : 1.f;
                    ar[q] += s * pr; ai[q] += s * pi;
                }
            }
            const int m = (__builtin_popcount(j) - __builtin_popcount(k)) & 3;
#pragma unroll
            for (int q = 0; q < 4; ++q)
                sv[q] = (m == 0) ? ar[q] : (m == 1) ? -ai[q] : (m == 2) ? -ar[q] : ai[q];
        };

        float s1[4], s2[4];
        evalS(4 * a + b, 4 * c + d, s1);
        evalS(4 * a + d, 4 * c + b, s2);
        const float u = ((a < c) ? 2.f : 1.f) * ((b < d) ? 1.f : 0.5f);
        fv4 gv; gv.x = u*(s1[0]+s2[0]); gv.y = u*(s1[1]+s2[1]);
        gv.z = u*(s1[2]+s2[2]); gv.w = u*(s1[3]+s2[3]);
        G4[ac * 10 + bd] = gv;
    }
    __syncthreads();

    // ---- phase 3: threads 0..80 basis change H = (1/16) T G T^T (verified R12) ----
    if (threadIdx.x < 81) {
        const int i = threadIdx.x / 9, j = threadIdx.x % 9;
        fv4 acc = (fv4)(0.f);
#pragma unroll
        for (int ac = 0; ac < 10; ++ac) {
            const float ti = TC[ac][i];
            fv4 tj = (fv4)(0.f);
#pragma unroll
            for (int bd = 0; bd < 10; ++bd)
                tj += G4[ac * 10 + bd] * TC[bd][j];
            acc += tj * ti;
        }
        hw[i * 9 + j] = acc * 0.0625f;
    }
}

__global__ void __launch_bounds__(256)
qlayer_main(const float4* __restrict__ x,
            const fv4* __restrict__ hw,
            fv4* __restrict__ out, int B)
{
    const int gi = blockIdx.x * 256 + threadIdx.x;
    if (gi >= B) return;

    const float4 xv = x[gi];
    const float cx0 = __cosf(xv.x), sx0 = __sinf(xv.x);   // full angles
    const float cx1 = __cosf(xv.y), sx1 = __sinf(xv.y);
    const float cx2 = __cosf(xv.z), sx2 = __sinf(xv.z);
    const float cx3 = __cosf(xv.w), sx3 = __sinf(xv.w);

    float u[8], v[8];
    u[0] = cx1;       u[1] = sx1;       u[2] = cx0;
    u[3] = cx0 * cx1; u[4] = cx0 * sx1;
    u[5] = sx0;       u[6] = sx0 * cx1; u[7] = sx0 * sx1;
    v[0] = cx3;       v[1] = sx3;       v[2] = cx2;
    v[3] = cx2 * cx3; v[4] = cx2 * sx3;
    v[5] = sx2;       v[6] = sx2 * cx3; v[7] = sx2 * sx3;

    fv4 o = (fv4)(0.f);
#pragma unroll
    for (int i = 0; i < 9; ++i) {
        // hw: uniform address, compile-time index, read-only __restrict__
        // -> s_load_dwordx4 (scalar pipe), zero vector-pipe cost.
        fv4 t = hw[i * 9];                       // j = 0 (v_0 = 1)
#pragma unroll
        for (int j = 1; j < 9; ++j)
            t += hw[i * 9 + j] * v[j - 1];
        o = (i == 0) ? t : o + t * u[i - 1];     // u_0 = 1
    }

    out[gi] = o;
}

extern "C" void kernel_launch(void* const* d_in, const int* in_sizes, int n_in,
                              void* d_out, int out_size, void* d_ws, size_t ws_size,
                              hipStream_t stream)
{
    const float4* x = (const float4*)d_in[0];
    const float* w  = (const float*)d_in[1];
    fv4* out        = (fv4*)d_out;
    fv4* hw         = (fv4*)d_ws;     // 81 * 16 B = 1296 B
    const int B = in_sizes[0] / NQ;

    qlayer_prep<<<1, 128, 0, stream>>>(w, hw);

    const int block = 256;
    const int grid = (B + block - 1) / block;    // E=1
    qlayer_main<<<grid, block, 0, stream>>>(x, hw, out, B);
}